// Round 1
// baseline (6141.513 us; speedup 1.0000x reference)
//
#include <hip/hip_runtime.h>
#include <math.h>

#define B_IMG 8
#define OPI 64
#define RPI 1024
#define N_OBJ 512       // B*OPI
#define R_REL 8192      // B*RPI
#define OBJ_DIM 4096
#define H 512
#define NOC 151
#define NRC 51
#define T_ITERS 3
#define IOU_THRESH 0.3f

#define BN 64
#define BK 16

enum { EPI_STORE = 0, EPI_BIAS = 1, EPI_ADDTO = 2, EPI_GATE = 3, EPI_NEWH = 4 };

// Generic fp32 GEMM: C(MxN) = [A1 | A2](MxK1+K2) @ [B1 ; B2] with fused epilogues.
// A row-major with lda; B row-major KxN with ldb.
// GATHER: A row m is h_obj[s[m]] + h_obj[o[m]] (s,o from ridx, stride 3, cols 1,2).
// EPI_GATE:  g = sigmoid(acc + bias[n]); n<N/2 -> Zout = g ; else RHout = g * Hb
// EPI_NEWH:  nv = tanh(acc + bias[n]); C = (1-Zin)*Hb + Zin*nv
template<int BM_, int TM_, int EPI, bool DUAL, bool GATHER>
__global__ __launch_bounds__(256) void gemm_k(
    int M, int N, int K1, int K2,
    const float* __restrict__ A1, int lda1,
    const float* __restrict__ A2, int lda2,
    const float* __restrict__ B1, int ldb1,
    const float* __restrict__ B2, int ldb2,
    const float* __restrict__ bias,
    float* __restrict__ C, int ldc,
    const int* __restrict__ ridx,
    const float* __restrict__ Hb, int ldh,
    const float* __restrict__ Zin,
    float* __restrict__ Zout,
    float* __restrict__ RHout)
{
  __shared__ __align__(16) float As[BK][BM_ + 4];
  __shared__ __align__(16) float Bs[BK][BN + 4];
  const int t  = threadIdx.x;
  const int tx = t & 15;
  const int ty = t >> 4;
  const int m0 = blockIdx.y * BM_;
  const int n0 = blockIdx.x * BN;
  const int Kt = K1 + K2;

  float acc[TM_][4];
#pragma unroll
  for (int i = 0; i < TM_; ++i)
#pragma unroll
    for (int j = 0; j < 4; ++j) acc[i][j] = 0.f;

  for (int k0 = 0; k0 < Kt; k0 += BK) {
    // ---- load A tile (BM_ x BK), store transposed As[kk][row]
#pragma unroll
    for (int i = 0; i < (BM_ * BK) / 256; ++i) {
      int e  = i * 256 + t;
      int kk = e & 15;
      int ar = e >> 4;
      int gm = m0 + ar;
      int gk = k0 + kk;
      float v = 0.f;
      if (gm < M && gk < Kt) {
        const float* Ap = A1; int lda = lda1; int kl = gk;
        if (DUAL && gk >= K1) { Ap = A2; lda = lda2; kl = gk - K1; }
        if (GATHER) {
          int si = ridx[gm * 3 + 1];
          int oi = ridx[gm * 3 + 2];
          v = Ap[si * lda + kl] + Ap[oi * lda + kl];
        } else {
          v = Ap[gm * lda + kl];
        }
      }
      As[kk][ar] = v;
    }
    // ---- load B tile (BK x BN)
#pragma unroll
    for (int i = 0; i < 4; ++i) {
      int e  = i * 256 + t;
      int bn = e & 63;
      int kk = e >> 6;
      int gn = n0 + bn;
      int gk = k0 + kk;
      float v = 0.f;
      if (gn < N && gk < Kt) {
        if (!DUAL || gk < K1) v = B1[gk * ldb1 + gn];
        else                  v = B2[(gk - K1) * ldb2 + gn];
      }
      Bs[kk][bn] = v;
    }
    __syncthreads();
    // ---- compute
#pragma unroll
    for (int kk = 0; kk < BK; ++kk) {
      float4 b4 = *(const float4*)&Bs[kk][tx * 4];
#pragma unroll
      for (int u = 0; u < TM_ / 4; ++u) {
        float4 a4 = *(const float4*)&As[kk][ty * TM_ + 4 * u];
        float av0 = a4.x, av1 = a4.y, av2 = a4.z, av3 = a4.w;
        acc[4*u+0][0] = fmaf(av0, b4.x, acc[4*u+0][0]);
        acc[4*u+0][1] = fmaf(av0, b4.y, acc[4*u+0][1]);
        acc[4*u+0][2] = fmaf(av0, b4.z, acc[4*u+0][2]);
        acc[4*u+0][3] = fmaf(av0, b4.w, acc[4*u+0][3]);
        acc[4*u+1][0] = fmaf(av1, b4.x, acc[4*u+1][0]);
        acc[4*u+1][1] = fmaf(av1, b4.y, acc[4*u+1][1]);
        acc[4*u+1][2] = fmaf(av1, b4.z, acc[4*u+1][2]);
        acc[4*u+1][3] = fmaf(av1, b4.w, acc[4*u+1][3]);
        acc[4*u+2][0] = fmaf(av2, b4.x, acc[4*u+2][0]);
        acc[4*u+2][1] = fmaf(av2, b4.y, acc[4*u+2][1]);
        acc[4*u+2][2] = fmaf(av2, b4.z, acc[4*u+2][2]);
        acc[4*u+2][3] = fmaf(av2, b4.w, acc[4*u+2][3]);
        acc[4*u+3][0] = fmaf(av3, b4.x, acc[4*u+3][0]);
        acc[4*u+3][1] = fmaf(av3, b4.y, acc[4*u+3][1]);
        acc[4*u+3][2] = fmaf(av3, b4.z, acc[4*u+3][2]);
        acc[4*u+3][3] = fmaf(av3, b4.w, acc[4*u+3][3]);
      }
    }
    __syncthreads();
  }

  // ---- epilogue
#pragma unroll
  for (int i = 0; i < TM_; ++i) {
    int gm = m0 + ty * TM_ + i;
    if (gm >= M) continue;
#pragma unroll
    for (int j = 0; j < 4; ++j) {
      int gn = n0 + tx * 4 + j;
      if (gn >= N) continue;
      float v = acc[i][j];
      if (EPI == EPI_STORE) {
        C[gm * ldc + gn] = v;
      } else if (EPI == EPI_BIAS) {
        C[gm * ldc + gn] = v + bias[gn];
      } else if (EPI == EPI_ADDTO) {
        C[gm * ldc + gn] += v;
      } else if (EPI == EPI_GATE) {
        float g = 1.f / (1.f + expf(-(v + bias[gn])));
        int half = N >> 1;
        if (gn < half) Zout[gm * half + gn] = g;
        else           RHout[gm * half + (gn - half)] = g * Hb[gm * ldh + (gn - half)];
      } else if (EPI == EPI_NEWH) {
        float nv = tanhf(v + bias[gn]);
        float z  = Zin[gm * N + gn];
        float h  = Hb[gm * ldh + gn];
        C[gm * ldc + gn] = (1.f - z) * h + z * nv;
      }
    }
  }
}

// row softmax over NOC=151 columns, one block per row
__global__ __launch_bounds__(256) void softmax_k(const float* __restrict__ X,
                                                 float* __restrict__ P)
{
  int row = blockIdx.x;
  int t = threadIdx.x;
  __shared__ float red[4];
  float x = (t < NOC) ? X[row * NOC + t] : -3.4e38f;
  float m = x;
#pragma unroll
  for (int o = 32; o > 0; o >>= 1) m = fmaxf(m, __shfl_xor(m, o, 64));
  if ((t & 63) == 0) red[t >> 6] = m;
  __syncthreads();
  float mm = fmaxf(fmaxf(red[0], red[1]), fmaxf(red[2], red[3]));
  float e = (t < NOC) ? expf(x - mm) : 0.f;
  float s = e;
#pragma unroll
  for (int o = 32; o > 0; o >>= 1) s += __shfl_xor(s, o, 64);
  __syncthreads();
  if ((t & 63) == 0) red[t >> 6] = s;
  __syncthreads();
  float ss = red[0] + red[1] + red[2] + red[3];
  if (t < NOC) P[row * NOC + t] = e / ss;
}

// m_obj[n] = sum over rels r in n's image of ((s==n)+(o==n)) * hm[r]
// deterministic (ascending r), no atomics. One block per object, 256 threads = 2 cols each.
__global__ __launch_bounds__(256) void m_obj_gather_k(const float* __restrict__ hm,
                                                      const int* __restrict__ ridx,
                                                      float* __restrict__ m_obj)
{
  int n = blockIdx.x;
  int im = n >> 6;
  int col = threadIdx.x;
  float acc0 = 0.f, acc1 = 0.f;
  int r0 = im * RPI, r1 = r0 + RPI;
  for (int r = r0; r < r1; ++r) {
    int s = ridx[r * 3 + 1];
    int o = ridx[r * 3 + 2];
    int cnt = (s == n) + (o == n);
    if (cnt) {
      float f = (float)cnt;
      acc0 = fmaf(f, hm[r * H + col], acc0);
      acc1 = fmaf(f, hm[r * H + col + 256], acc1);
    }
  }
  m_obj[n * H + col] = acc0;
  m_obj[n * H + col + 256] = acc1;
}

// Per-class NMS. block = class (1..150), 512 threads = boxes.
// Stable descending sort by (score desc, idx asc) == argsort(-scores) stable.
__global__ __launch_bounds__(512) void nms_k(const float* __restrict__ probs2,
                                             const float* __restrict__ boxes,
                                             float* __restrict__ keepmask)
{
  int c = blockIdx.x + 1;
  int t = threadIdx.x;
  __shared__ float sc[512];
  __shared__ int   si[512];
  __shared__ float bx0[512], by0[512], bx1[512], by1[512], sar[512];
  __shared__ int   skeep[512];

  sc[t] = probs2[t * NOC + c];
  si[t] = t;
  __syncthreads();

  for (int k = 2; k <= 512; k <<= 1) {
    for (int j = k >> 1; j > 0; j >>= 1) {
      int p = t ^ j;
      if (p > t) {
        float s1 = sc[t], s2 = sc[p];
        int   i1 = si[t], i2 = si[p];
        bool tBefore = (s1 > s2) || (s1 == s2 && i1 < i2);
        bool up = ((t & k) == 0);
        if (up != tBefore) { sc[t] = s2; sc[p] = s1; si[t] = i2; si[p] = i1; }
      }
      __syncthreads();
    }
  }

  {
    const float* b = &boxes[(si[t] * NOC + c) * 4];
    float x0 = b[0], y0 = b[1], x1 = b[2], y1 = b[3];
    bx0[t] = x0; by0[t] = y0; bx1[t] = x1; by1[t] = y1;
    sar[t] = (x1 - x0) * (y1 - y0);
    skeep[t] = 1;
  }
  __syncthreads();

  for (int i = 0; i < 511; ++i) {
    if (skeep[i] && t > i && skeep[t]) {
      float lx = fmaxf(bx0[i], bx0[t]);
      float ly = fmaxf(by0[i], by0[t]);
      float rx = fminf(bx1[i], bx1[t]);
      float ry = fminf(by1[i], by1[t]);
      float w = fmaxf(rx - lx, 0.f);
      float h = fmaxf(ry - ly, 0.f);
      float inter = w * h;
      float iou = inter / (sar[i] + sar[t] - inter + 1e-9f);
      if (iou > IOU_THRESH) skeep[t] = 0;
    }
    __syncthreads();
  }

  keepmask[(c - 1) * N_OBJ + si[t]] = skeep[t] ? 1.f : 0.f;
}

// obj_preds[i] = argmax_c in [0,150) of keepmask[c][i]*probs2[i][c+1], +1 (first max wins)
__global__ void pred_k(const float* __restrict__ probs2,
                       const float* __restrict__ keepmask,
                       float* __restrict__ out)
{
  int i = threadIdx.x + blockIdx.x * 256;
  if (i >= N_OBJ) return;
  float best = -1.f;
  int bc = 0;
  for (int c = 0; c < NOC - 1; ++c) {
    float v = keepmask[c * N_OBJ + i] * probs2[i * NOC + c + 1];
    if (v > best) { best = v; bc = c; }
  }
  out[i] = (float)(bc + 1);
}

extern "C" void kernel_launch(void* const* d_in, const int* in_sizes, int n_in,
                              void* d_out, int out_size, void* d_ws, size_t ws_size,
                              hipStream_t stream) {
  const float* obj_fmaps  = (const float*)d_in[1];
  const float* obj_logits = (const float*)d_in[2];
  const int*   rel_inds   = (const int*)d_in[3];
  const float* vr         = (const float*)d_in[4];
  const float* boxes      = (const float*)d_in[5];
  const float* W_obj_proj = (const float*)d_in[6];
  const float* b_obj_proj = (const float*)d_in[7];
  const float* W_rel_proj = (const float*)d_in[8];
  const float* b_rel_proj = (const float*)d_in[9];
  const float* W_emb      = (const float*)d_in[10];
  const float* W_msg_rel  = (const float*)d_in[11];
  const float* W_msg_obj  = (const float*)d_in[12];
  const float* W_gru_obj  = (const float*)d_in[13];
  const float* U_gru_obj  = (const float*)d_in[14];
  const float* b_gru_obj  = (const float*)d_in[15];
  const float* W_gru_rel  = (const float*)d_in[16];
  const float* U_gru_rel  = (const float*)d_in[17];
  const float* b_gru_rel  = (const float*)d_in[18];
  const float* W_cls_rel  = (const float*)d_in[19];
  const float* b_cls_rel  = (const float*)d_in[20];
  const float* W_cls_obj  = (const float*)d_in[21];
  const float* b_cls_obj  = (const float*)d_in[22];

  float* ws = (float*)d_ws;
  const size_t RH = (size_t)R_REL * H;
  const size_t NH = (size_t)N_OBJ * H;
  float* h_rel  = ws;
  float* m_rel  = h_rel  + RH;
  float* z_rel  = m_rel  + RH;   // aliased with hm (hm dead before z written)
  float* rh_rel = z_rel  + RH;
  float* h_obj  = rh_rel + RH;
  float* m_obj  = h_obj  + NH;
  float* z_obj  = m_obj  + NH;
  float* rh_obj = z_obj  + NH;
  float* obj_probs  = rh_obj + NH;
  float* obj_probs2 = obj_probs  + (size_t)N_OBJ * NOC;
  float* keepmask   = obj_probs2 + (size_t)N_OBJ * NOC;
  float* hm = z_rel;

  float* out_logits = (float*)d_out;                          // 512*151
  float* out_preds  = out_logits + (size_t)N_OBJ * NOC;       // 512
  float* out_rel    = out_preds + N_OBJ;                      // 8192*51

  dim3 blk(256);

  // obj_probs = softmax(obj_logits)
  softmax_k<<<N_OBJ, 256, 0, stream>>>(obj_logits, obj_probs);

  // h_obj = obj_fmaps @ W_obj_proj + b_obj_proj
  gemm_k<64, 4, EPI_BIAS, false, false><<<dim3(H / BN, N_OBJ / 64), blk, 0, stream>>>(
      N_OBJ, H, OBJ_DIM, 0, obj_fmaps, OBJ_DIM, nullptr, 0,
      W_obj_proj, H, nullptr, 0, b_obj_proj, h_obj, H,
      nullptr, nullptr, 0, nullptr, nullptr, nullptr);
  // h_obj += obj_probs @ W_emb
  gemm_k<64, 4, EPI_ADDTO, false, false><<<dim3(H / BN, N_OBJ / 64), blk, 0, stream>>>(
      N_OBJ, H, NOC, 0, obj_probs, NOC, nullptr, 0,
      W_emb, H, nullptr, 0, nullptr, h_obj, H,
      nullptr, nullptr, 0, nullptr, nullptr, nullptr);
  // h_rel = vr @ W_rel_proj + b_rel_proj
  gemm_k<128, 8, EPI_BIAS, false, false><<<dim3(H / BN, R_REL / 128), blk, 0, stream>>>(
      R_REL, H, OBJ_DIM, 0, vr, OBJ_DIM, nullptr, 0,
      W_rel_proj, H, nullptr, 0, b_rel_proj, h_rel, H,
      nullptr, nullptr, 0, nullptr, nullptr, nullptr);

  for (int it = 0; it < T_ITERS; ++it) {
    // m_rel = (h_obj[s] + h_obj[o]) @ W_msg_rel
    gemm_k<128, 8, EPI_STORE, false, true><<<dim3(H / BN, R_REL / 128), blk, 0, stream>>>(
        R_REL, H, H, 0, h_obj, H, nullptr, 0,
        W_msg_rel, H, nullptr, 0, nullptr, m_rel, H,
        rel_inds, nullptr, 0, nullptr, nullptr, nullptr);
    // hm = h_rel @ W_msg_obj
    gemm_k<128, 8, EPI_STORE, false, false><<<dim3(H / BN, R_REL / 128), blk, 0, stream>>>(
        R_REL, H, H, 0, h_rel, H, nullptr, 0,
        W_msg_obj, H, nullptr, 0, nullptr, hm, H,
        nullptr, nullptr, 0, nullptr, nullptr, nullptr);
    // m_obj scatter-free gather
    m_obj_gather_k<<<N_OBJ, 256, 0, stream>>>(hm, rel_inds, m_obj);

    // GRU rel: gates (z, r*h)
    gemm_k<128, 8, EPI_GATE, true, false><<<dim3(2 * H / BN, R_REL / 128), blk, 0, stream>>>(
        R_REL, 2 * H, H, H, m_rel, H, h_rel, H,
        W_gru_rel, 3 * H, U_gru_rel, 3 * H, b_gru_rel, nullptr, 0,
        nullptr, h_rel, H, nullptr, z_rel, rh_rel);
    // GRU rel: candidate + h update (in place)
    gemm_k<128, 8, EPI_NEWH, true, false><<<dim3(H / BN, R_REL / 128), blk, 0, stream>>>(
        R_REL, H, H, H, m_rel, H, rh_rel, H,
        W_gru_rel + 2 * H, 3 * H, U_gru_rel + 2 * H, 3 * H, b_gru_rel + 2 * H,
        h_rel, H, nullptr, h_rel, H, z_rel, nullptr, nullptr);

    // GRU obj: gates
    gemm_k<64, 4, EPI_GATE, true, false><<<dim3(2 * H / BN, N_OBJ / 64), blk, 0, stream>>>(
        N_OBJ, 2 * H, H, H, m_obj, H, h_obj, H,
        W_gru_obj, 3 * H, U_gru_obj, 3 * H, b_gru_obj, nullptr, 0,
        nullptr, h_obj, H, nullptr, z_obj, rh_obj);
    // GRU obj: candidate + h update
    gemm_k<64, 4, EPI_NEWH, true, false><<<dim3(H / BN, N_OBJ / 64), blk, 0, stream>>>(
        N_OBJ, H, H, H, m_obj, H, rh_obj, H,
        W_gru_obj + 2 * H, 3 * H, U_gru_obj + 2 * H, 3 * H, b_gru_obj + 2 * H,
        h_obj, H, nullptr, h_obj, H, z_obj, nullptr, nullptr);
  }

  // rel_logits = h_rel @ W_cls_rel + b_cls_rel   (N=51)
  gemm_k<128, 8, EPI_BIAS, false, false><<<dim3((NRC + BN - 1) / BN, R_REL / 128), blk, 0, stream>>>(
      R_REL, NRC, H, 0, h_rel, H, nullptr, 0,
      W_cls_rel, NRC, nullptr, 0, b_cls_rel, out_rel, NRC,
      nullptr, nullptr, 0, nullptr, nullptr, nullptr);
  // obj_logits_out = h_obj @ W_cls_obj + b_cls_obj (N=151)
  gemm_k<64, 4, EPI_BIAS, false, false><<<dim3((NOC + BN - 1) / BN, N_OBJ / 64), blk, 0, stream>>>(
      N_OBJ, NOC, H, 0, h_obj, H, nullptr, 0,
      W_cls_obj, NOC, nullptr, 0, b_cls_obj, out_logits, NOC,
      nullptr, nullptr, 0, nullptr, nullptr, nullptr);

  // obj_probs2 = softmax(obj_logits_out)
  softmax_k<<<N_OBJ, 256, 0, stream>>>(out_logits, obj_probs2);
  // per-class NMS
  nms_k<<<NOC - 1, 512, 0, stream>>>(obj_probs2, boxes, keepmask);
  // obj_preds
  pred_k<<<2, 256, 0, stream>>>(obj_probs2, keepmask, out_preds);
}

// Round 2
// 2598.971 us; speedup vs baseline: 2.3631x; 2.3631x over previous
//
#include <hip/hip_runtime.h>
#include <math.h>

#define OPI 64
#define RPI 1024
#define N_OBJ 512       // B*OPI
#define R_REL 8192      // B*RPI
#define OBJ_DIM 4096
#define H 512
#define NOC 151
#define NRC 51
#define T_ITERS 3
#define IOU_THRESH 0.3f

typedef unsigned short u16;
typedef unsigned int u32;
typedef __attribute__((ext_vector_type(4))) float f32x4;
typedef __attribute__((ext_vector_type(8))) short bf16x8;
typedef __attribute__((ext_vector_type(4))) short s16x4;
typedef __attribute__((ext_vector_type(8))) short s16x8;

enum { EPI_STORE = 0, EPI_BIAS = 1, EPI_ADDTO = 2, EPI_GATE = 3, EPI_NEWH = 4 };

__device__ inline u16 f2bf(float x) {
  u32 u = __float_as_uint(x);
  u32 r = (u + 0x7fffu + ((u >> 16) & 1u)) >> 16;
  return (u16)r;
}
__device__ inline float bf2f(u16 h) { return __uint_as_float(((u32)h) << 16); }

// ---------------------------------------------------------------------------
// Weight prep: out[n][k] = (k<K1 ? W1[k][coloff+n] : k-K1<K2 ? W2[k-K1][coloff+n] : 0)
// split into bf16 hi/lo.
// ---------------------------------------------------------------------------
__global__ __launch_bounds__(256) void prep_bt(
    const float* __restrict__ W1, int ld1, int K1,
    const float* __restrict__ W2, int ld2, int K2,
    int coloff, int N, int Kpad,
    u16* __restrict__ outh, u16* __restrict__ outl)
{
  int idx = blockIdx.x * 256 + threadIdx.x;
  if (idx >= N * Kpad) return;
  int n = idx / Kpad;
  int k = idx - n * Kpad;
  float v = 0.f;
  if (k < K1) v = W1[(size_t)k * ld1 + coloff + n];
  else if (k - K1 < K2) v = W2[(size_t)(k - K1) * ld2 + coloff + n];
  u16 h = f2bf(v);
  outh[(size_t)n * Kpad + k] = h;
  outl[(size_t)n * Kpad + k] = f2bf(v - bf2f(h));
}

// ---------------------------------------------------------------------------
// Split-bf16 MFMA GEMM: C = [A1|A2] @ B with A split to hi/lo on the fly and
// B pre-transposed/split (Bt[N][Kpad] bf16 hi/lo).
// C ~= Ah@Bh + Ah@Bl + Al@Bh  (fp32 accumulate in AGPRs).
// Tile 128x128, 4 waves (2x2), mfma_f32_16x16x32_bf16, BK=32.
// LDS layout: tile[row][k] at element row*32 + (( (k>>3) ^ ((row>>1)&3) )<<3) + (k&7)
//   -> ds_read_b128 frag reads are 2-way bank aliased (free).
// ---------------------------------------------------------------------------
template<int EPI, bool DUAL, bool GATHER>
__global__ __launch_bounds__(256) void mgemm_k(
    int M, int N, int K1, int K2, int nkt,
    const float* __restrict__ A1, int lda1,
    const float* __restrict__ A2, int lda2,
    const u16* __restrict__ Bth, const u16* __restrict__ Btl,
    const float* __restrict__ bias,
    float* __restrict__ C, int ldc,
    const int* __restrict__ ridx,
    const float* __restrict__ Hb, int ldh,
    const float* __restrict__ Zin,
    float* __restrict__ Zout, float* __restrict__ RHout)
{
  __shared__ u16 lAh[128 * 32];
  __shared__ u16 lAl[128 * 32];
  __shared__ u16 lBh[128 * 32];
  __shared__ u16 lBl[128 * 32];
  const int t = threadIdx.x;
  const int lane = t & 63;
  const int wid = t >> 6;
  const int wm = wid >> 1, wn = wid & 1;
  const int m0 = blockIdx.y * 128;
  const int n0 = blockIdx.x * 128;
  const int Kpad = nkt * 32;

  f32x4 acc[4][4];
#pragma unroll
  for (int m = 0; m < 4; ++m)
#pragma unroll
    for (int n = 0; n < 4; ++n) acc[m][n] = f32x4{0.f, 0.f, 0.f, 0.f};

  const int a_row = t >> 3;     // +i*32 (8 float4-groups per 32-wide row)
  const int a_kq  = t & 7;
  int g_si[4], g_oi[4];
  if (GATHER) {
#pragma unroll
    for (int i = 0; i < 4; ++i) {
      int gm = m0 + a_row + i * 32;
      g_si[i] = ridx[gm * 3 + 1];
      g_oi[i] = ridx[gm * 3 + 2];
    }
  }
  const int b_row  = t >> 2;    // +i*64 (4 16B-chunks per 32-wide row)
  const int b_slot = t & 3;

  for (int kt = 0; kt < nkt; ++kt) {
    const int k0 = kt * 32;
    // ---- stage A (fp32 -> split bf16 hi/lo)
#pragma unroll
    for (int i = 0; i < 4; ++i) {
      const int row = a_row + i * 32;
      const int gm = m0 + row;
      const int kk = a_kq * 4;
      const int gk = k0 + kk;
      float x0, x1, x2, x3;
      if (GATHER) {
        const float4 va = *(const float4*)&A1[(size_t)g_si[i] * lda1 + gk];
        const float4 vb = *(const float4*)&A1[(size_t)g_oi[i] * lda1 + gk];
        x0 = va.x + vb.x; x1 = va.y + vb.y; x2 = va.z + vb.z; x3 = va.w + vb.w;
      } else if (!DUAL) {
        const float4 v = *(const float4*)&A1[(size_t)gm * lda1 + gk];
        x0 = v.x; x1 = v.y; x2 = v.z; x3 = v.w;
      } else {
        if (gk + 3 < K1) {
          const float4 v = *(const float4*)&A1[(size_t)gm * lda1 + gk];
          x0 = v.x; x1 = v.y; x2 = v.z; x3 = v.w;
        } else if (gk >= K1 && gk + 3 < K1 + K2 && (lda2 & 3) == 0) {
          const float4 v = *(const float4*)&A2[(size_t)gm * lda2 + (gk - K1)];
          x0 = v.x; x1 = v.y; x2 = v.z; x3 = v.w;
        } else {
          float xs[4];
#pragma unroll
          for (int e = 0; e < 4; ++e) {
            int gke = gk + e;
            float xv = 0.f;
            if (gke < K1) xv = A1[(size_t)gm * lda1 + gke];
            else if (gke < K1 + K2) xv = A2[(size_t)gm * lda2 + (gke - K1)];
            xs[e] = xv;
          }
          x0 = xs[0]; x1 = xs[1]; x2 = xs[2]; x3 = xs[3];
        }
      }
      u16 h0 = f2bf(x0), h1 = f2bf(x1), h2 = f2bf(x2), h3 = f2bf(x3);
      s16x4 vh = { (short)h0, (short)h1, (short)h2, (short)h3 };
      s16x4 vl = { (short)f2bf(x0 - bf2f(h0)), (short)f2bf(x1 - bf2f(h1)),
                   (short)f2bf(x2 - bf2f(h2)), (short)f2bf(x3 - bf2f(h3)) };
      const int base = row * 32 + (((a_kq >> 1) ^ ((row >> 1) & 3)) << 3) + (a_kq & 1) * 4;
      *reinterpret_cast<s16x4*>(&lAh[base]) = vh;
      *reinterpret_cast<s16x4*>(&lAl[base]) = vl;
    }
    // ---- stage B (pre-split bf16)
#pragma unroll
    for (int i = 0; i < 2; ++i) {
      const int row = b_row + i * 64;
      const size_t goff = (size_t)(n0 + row) * Kpad + k0 + b_slot * 8;
      s16x8 vh = *reinterpret_cast<const s16x8*>(&Bth[goff]);
      s16x8 vl = *reinterpret_cast<const s16x8*>(&Btl[goff]);
      const int base = row * 32 + ((b_slot ^ ((row >> 1) & 3)) << 3);
      *reinterpret_cast<s16x8*>(&lBh[base]) = vh;
      *reinterpret_cast<s16x8*>(&lBl[base]) = vl;
    }
    __syncthreads();
    // ---- fragments + MFMA
    const int fr = lane & 15;
    const int kg = lane >> 4;
    bf16x8 ah[4], al[4], bh[4], bl[4];
#pragma unroll
    for (int m = 0; m < 4; ++m) {
      const int r = wm * 64 + m * 16 + fr;
      const int addr = r * 32 + ((kg ^ ((r >> 1) & 3)) << 3);
      ah[m] = *reinterpret_cast<const bf16x8*>(&lAh[addr]);
      al[m] = *reinterpret_cast<const bf16x8*>(&lAl[addr]);
    }
#pragma unroll
    for (int n = 0; n < 4; ++n) {
      const int r = wn * 64 + n * 16 + fr;
      const int addr = r * 32 + ((kg ^ ((r >> 1) & 3)) << 3);
      bh[n] = *reinterpret_cast<const bf16x8*>(&lBh[addr]);
      bl[n] = *reinterpret_cast<const bf16x8*>(&lBl[addr]);
    }
#pragma unroll
    for (int m = 0; m < 4; ++m)
#pragma unroll
      for (int n = 0; n < 4; ++n) {
        acc[m][n] = __builtin_amdgcn_mfma_f32_16x16x32_bf16(ah[m], bh[n], acc[m][n], 0, 0, 0);
        acc[m][n] = __builtin_amdgcn_mfma_f32_16x16x32_bf16(ah[m], bl[n], acc[m][n], 0, 0, 0);
        acc[m][n] = __builtin_amdgcn_mfma_f32_16x16x32_bf16(al[m], bh[n], acc[m][n], 0, 0, 0);
      }
    __syncthreads();
  }

  // ---- epilogue (C/D layout: col = lane&15, row = (lane>>4)*4 + j)
  const int col = lane & 15;
  const int rb = (lane >> 4) * 4;
#pragma unroll
  for (int m = 0; m < 4; ++m) {
#pragma unroll
    for (int n = 0; n < 4; ++n) {
      const int gn = n0 + wn * 64 + n * 16 + col;
#pragma unroll
      for (int j = 0; j < 4; ++j) {
        const int gm = m0 + wm * 64 + m * 16 + rb + j;
        float v = acc[m][n][j];
        if (EPI == EPI_STORE) {
          C[(size_t)gm * ldc + gn] = v;
        } else if (EPI == EPI_BIAS) {
          C[(size_t)gm * ldc + gn] = v + bias[gn];
        } else if (EPI == EPI_GATE) {
          float g = 1.f / (1.f + expf(-(v + bias[gn])));
          int half = N >> 1;
          if (gn < half) Zout[(size_t)gm * half + gn] = g;
          else RHout[(size_t)gm * half + (gn - half)] = g * Hb[(size_t)gm * ldh + (gn - half)];
        } else if (EPI == EPI_NEWH) {
          float nv = tanhf(v + bias[gn]);
          float z = Zin[(size_t)gm * N + gn];
          float h = Hb[(size_t)gm * ldh + gn];
          C[(size_t)gm * ldc + gn] = (1.f - z) * h + z * nv;
        }
      }
    }
  }
}

// ---------------------------------------------------------------------------
// fp32 vector GEMM (kept for the small classifier outputs N=51/151)
// ---------------------------------------------------------------------------
template<int BM_, int TM_, int EPI>
__global__ __launch_bounds__(256) void gemm_k(
    int M, int N, int K1,
    const float* __restrict__ A1, int lda1,
    const float* __restrict__ B1, int ldb1,
    const float* __restrict__ bias,
    float* __restrict__ C, int ldc)
{
  __shared__ __align__(16) float As[16][BM_ + 4];
  __shared__ __align__(16) float Bs[16][64 + 4];
  const int t  = threadIdx.x;
  const int tx = t & 15;
  const int ty = t >> 4;
  const int m0 = blockIdx.y * BM_;
  const int n0 = blockIdx.x * 64;

  float acc[TM_][4];
#pragma unroll
  for (int i = 0; i < TM_; ++i)
#pragma unroll
    for (int j = 0; j < 4; ++j) acc[i][j] = 0.f;

  for (int k0 = 0; k0 < K1; k0 += 16) {
#pragma unroll
    for (int i = 0; i < (BM_ * 16) / 256; ++i) {
      int e  = i * 256 + t;
      int kk = e & 15;
      int ar = e >> 4;
      int gm = m0 + ar;
      int gk = k0 + kk;
      float v = 0.f;
      if (gm < M && gk < K1) v = A1[(size_t)gm * lda1 + gk];
      As[kk][ar] = v;
    }
#pragma unroll
    for (int i = 0; i < 4; ++i) {
      int e  = i * 256 + t;
      int bn = e & 63;
      int kk = e >> 6;
      int gn = n0 + bn;
      int gk = k0 + kk;
      float v = 0.f;
      if (gn < N && gk < K1) v = B1[(size_t)gk * ldb1 + gn];
      Bs[kk][bn] = v;
    }
    __syncthreads();
#pragma unroll
    for (int kk = 0; kk < 16; ++kk) {
      float4 b4 = *(const float4*)&Bs[kk][tx * 4];
#pragma unroll
      for (int u = 0; u < TM_ / 4; ++u) {
        float4 a4 = *(const float4*)&As[kk][ty * TM_ + 4 * u];
        float av[4] = {a4.x, a4.y, a4.z, a4.w};
#pragma unroll
        for (int q = 0; q < 4; ++q) {
          acc[4*u+q][0] = fmaf(av[q], b4.x, acc[4*u+q][0]);
          acc[4*u+q][1] = fmaf(av[q], b4.y, acc[4*u+q][1]);
          acc[4*u+q][2] = fmaf(av[q], b4.z, acc[4*u+q][2]);
          acc[4*u+q][3] = fmaf(av[q], b4.w, acc[4*u+q][3]);
        }
      }
    }
    __syncthreads();
  }
#pragma unroll
  for (int i = 0; i < TM_; ++i) {
    int gm = m0 + ty * TM_ + i;
    if (gm >= M) continue;
#pragma unroll
    for (int j = 0; j < 4; ++j) {
      int gn = n0 + tx * 4 + j;
      if (gn >= N) continue;
      float v = acc[i][j];
      if (EPI == EPI_BIAS) v += bias[gn];
      C[(size_t)gm * ldc + gn] = v;
    }
  }
}

// row softmax over NOC=151 columns, one block per row
__global__ __launch_bounds__(256) void softmax_k(const float* __restrict__ X,
                                                 float* __restrict__ P)
{
  int row = blockIdx.x;
  int t = threadIdx.x;
  __shared__ float red[4];
  float x = (t < NOC) ? X[row * NOC + t] : -3.4e38f;
  float m = x;
#pragma unroll
  for (int o = 32; o > 0; o >>= 1) m = fmaxf(m, __shfl_xor(m, o, 64));
  if ((t & 63) == 0) red[t >> 6] = m;
  __syncthreads();
  float mm = fmaxf(fmaxf(red[0], red[1]), fmaxf(red[2], red[3]));
  float e = (t < NOC) ? expf(x - mm) : 0.f;
  float s = e;
#pragma unroll
  for (int o = 32; o > 0; o >>= 1) s += __shfl_xor(s, o, 64);
  __syncthreads();
  if ((t & 63) == 0) red[t >> 6] = s;
  __syncthreads();
  float ss = red[0] + red[1] + red[2] + red[3];
  if (t < NOC) P[row * NOC + t] = e / ss;
}

// deterministic scatter-free m_obj
__global__ __launch_bounds__(256) void m_obj_gather_k(const float* __restrict__ hm,
                                                      const int* __restrict__ ridx,
                                                      float* __restrict__ m_obj)
{
  int n = blockIdx.x;
  int im = n >> 6;
  int col = threadIdx.x;
  float acc0 = 0.f, acc1 = 0.f;
  int r0 = im * RPI, r1 = r0 + RPI;
  for (int r = r0; r < r1; ++r) {
    int s = ridx[r * 3 + 1];
    int o = ridx[r * 3 + 2];
    int cnt = (s == n) + (o == n);
    if (cnt) {
      float f = (float)cnt;
      acc0 = fmaf(f, hm[r * H + col], acc0);
      acc1 = fmaf(f, hm[r * H + col + 256], acc1);
    }
  }
  m_obj[n * H + col] = acc0;
  m_obj[n * H + col + 256] = acc1;
}

// per-class NMS (stable descending bitonic sort + greedy suppression)
__global__ __launch_bounds__(512) void nms_k(const float* __restrict__ probs2,
                                             const float* __restrict__ boxes,
                                             float* __restrict__ keepmask)
{
  int c = blockIdx.x + 1;
  int t = threadIdx.x;
  __shared__ float sc[512];
  __shared__ int   si[512];
  __shared__ float bx0[512], by0[512], bx1[512], by1[512], sar[512];
  __shared__ int   skeep[512];

  sc[t] = probs2[t * NOC + c];
  si[t] = t;
  __syncthreads();

  for (int k = 2; k <= 512; k <<= 1) {
    for (int j = k >> 1; j > 0; j >>= 1) {
      int p = t ^ j;
      if (p > t) {
        float s1 = sc[t], s2 = sc[p];
        int   i1 = si[t], i2 = si[p];
        bool tBefore = (s1 > s2) || (s1 == s2 && i1 < i2);
        bool up = ((t & k) == 0);
        if (up != tBefore) { sc[t] = s2; sc[p] = s1; si[t] = i2; si[p] = i1; }
      }
      __syncthreads();
    }
  }

  {
    const float* b = &boxes[(si[t] * NOC + c) * 4];
    float x0 = b[0], y0 = b[1], x1 = b[2], y1 = b[3];
    bx0[t] = x0; by0[t] = y0; bx1[t] = x1; by1[t] = y1;
    sar[t] = (x1 - x0) * (y1 - y0);
    skeep[t] = 1;
  }
  __syncthreads();

  for (int i = 0; i < 511; ++i) {
    if (skeep[i] && t > i && skeep[t]) {
      float lx = fmaxf(bx0[i], bx0[t]);
      float ly = fmaxf(by0[i], by0[t]);
      float rx = fminf(bx1[i], bx1[t]);
      float ry = fminf(by1[i], by1[t]);
      float w = fmaxf(rx - lx, 0.f);
      float h = fmaxf(ry - ly, 0.f);
      float inter = w * h;
      float iou = inter / (sar[i] + sar[t] - inter + 1e-9f);
      if (iou > IOU_THRESH) skeep[t] = 0;
    }
    __syncthreads();
  }

  keepmask[(c - 1) * N_OBJ + si[t]] = skeep[t] ? 1.f : 0.f;
}

__global__ void pred_k(const float* __restrict__ probs2,
                       const float* __restrict__ keepmask,
                       float* __restrict__ out)
{
  int i = threadIdx.x + blockIdx.x * 256;
  if (i >= N_OBJ) return;
  float best = -1.f;
  int bc = 0;
  for (int c = 0; c < NOC - 1; ++c) {
    float v = keepmask[c * N_OBJ + i] * probs2[i * NOC + c + 1];
    if (v > best) { best = v; bc = c; }
  }
  out[i] = (float)(bc + 1);
}

extern "C" void kernel_launch(void* const* d_in, const int* in_sizes, int n_in,
                              void* d_out, int out_size, void* d_ws, size_t ws_size,
                              hipStream_t stream) {
  const float* obj_fmaps  = (const float*)d_in[1];
  const float* obj_logits = (const float*)d_in[2];
  const int*   rel_inds   = (const int*)d_in[3];
  const float* vr         = (const float*)d_in[4];
  const float* boxes      = (const float*)d_in[5];
  const float* W_obj_proj = (const float*)d_in[6];
  const float* b_obj_proj = (const float*)d_in[7];
  const float* W_rel_proj = (const float*)d_in[8];
  const float* b_rel_proj = (const float*)d_in[9];
  const float* W_emb      = (const float*)d_in[10];
  const float* W_msg_rel  = (const float*)d_in[11];
  const float* W_msg_obj  = (const float*)d_in[12];
  const float* W_gru_obj  = (const float*)d_in[13];
  const float* U_gru_obj  = (const float*)d_in[14];
  const float* b_gru_obj  = (const float*)d_in[15];
  const float* W_gru_rel  = (const float*)d_in[16];
  const float* U_gru_rel  = (const float*)d_in[17];
  const float* b_gru_rel  = (const float*)d_in[18];
  const float* W_cls_rel  = (const float*)d_in[19];
  const float* b_cls_rel  = (const float*)d_in[20];
  const float* W_cls_obj  = (const float*)d_in[21];
  const float* b_cls_obj  = (const float*)d_in[22];

  float* ws = (float*)d_ws;
  const size_t RH = (size_t)R_REL * H;
  const size_t NH = (size_t)N_OBJ * H;
  float* h_rel  = ws;
  float* m_rel  = h_rel  + RH;
  float* z_rel  = m_rel  + RH;   // aliased with hm (hm dead before z written)
  float* rh_rel = z_rel  + RH;
  float* h_obj  = rh_rel + RH;
  float* m_obj  = h_obj  + NH;
  float* z_obj  = m_obj  + NH;
  float* rh_obj = z_obj  + NH;
  float* obj_probs  = rh_obj + NH;
  float* obj_probs2 = obj_probs  + (size_t)N_OBJ * NOC;
  float* keepmask   = obj_probs2 + (size_t)N_OBJ * NOC;
  float* hm = z_rel;
  float* fend = keepmask + (size_t)(NOC - 1) * N_OBJ;

  // bf16 hi/lo pre-transposed weight buffers
  u16* bt = (u16*)fend;
  const int KP_HOBJ = 4256;   // 4096 + 151 padded to 32
  const int KP_HREL = 4096;
  const int KP_MSG  = 512;
  const int KP_GRU  = 1024;
  u16* bt_hobj_h = bt;                    u16* bt_hobj_l = bt_hobj_h + (size_t)H * KP_HOBJ;
  u16* bt_hrel_h = bt_hobj_l + (size_t)H * KP_HOBJ;  u16* bt_hrel_l = bt_hrel_h + (size_t)H * KP_HREL;
  u16* bt_mrel_h = bt_hrel_l + (size_t)H * KP_HREL;  u16* bt_mrel_l = bt_mrel_h + (size_t)H * KP_MSG;
  u16* bt_hm_h   = bt_mrel_l + (size_t)H * KP_MSG;   u16* bt_hm_l   = bt_hm_h   + (size_t)H * KP_MSG;
  u16* bt_gr_h   = bt_hm_l   + (size_t)H * KP_MSG;   u16* bt_gr_l   = bt_gr_h   + (size_t)2 * H * KP_GRU;
  u16* bt_nr_h   = bt_gr_l   + (size_t)2 * H * KP_GRU; u16* bt_nr_l = bt_nr_h   + (size_t)H * KP_GRU;
  u16* bt_go_h   = bt_nr_l   + (size_t)H * KP_GRU;   u16* bt_go_l   = bt_go_h   + (size_t)2 * H * KP_GRU;
  u16* bt_no_h   = bt_go_l   + (size_t)2 * H * KP_GRU; u16* bt_no_l = bt_no_h   + (size_t)H * KP_GRU;

  float* out_logits = (float*)d_out;                    // 512*151
  float* out_preds  = out_logits + (size_t)N_OBJ * NOC; // 512
  float* out_rel    = out_preds + N_OBJ;                // 8192*51

  dim3 blk(256);
#define PREP(W1, ld1, K1, W2, ld2, K2, coff, NN, KP, oh, ol) \
  prep_bt<<<((NN) * (KP) + 255) / 256, 256, 0, stream>>>(W1, ld1, K1, W2, ld2, K2, coff, NN, KP, oh, ol)

  PREP(W_obj_proj, H, OBJ_DIM, W_emb, H, NOC, 0, H, KP_HOBJ, bt_hobj_h, bt_hobj_l);
  PREP(W_rel_proj, H, OBJ_DIM, (const float*)nullptr, 0, 0, 0, H, KP_HREL, bt_hrel_h, bt_hrel_l);
  PREP(W_msg_rel, H, H, (const float*)nullptr, 0, 0, 0, H, KP_MSG, bt_mrel_h, bt_mrel_l);
  PREP(W_msg_obj, H, H, (const float*)nullptr, 0, 0, 0, H, KP_MSG, bt_hm_h, bt_hm_l);
  PREP(W_gru_rel, 3 * H, H, U_gru_rel, 3 * H, H, 0, 2 * H, KP_GRU, bt_gr_h, bt_gr_l);
  PREP(W_gru_rel, 3 * H, H, U_gru_rel, 3 * H, H, 2 * H, H, KP_GRU, bt_nr_h, bt_nr_l);
  PREP(W_gru_obj, 3 * H, H, U_gru_obj, 3 * H, H, 0, 2 * H, KP_GRU, bt_go_h, bt_go_l);
  PREP(W_gru_obj, 3 * H, H, U_gru_obj, 3 * H, H, 2 * H, H, KP_GRU, bt_no_h, bt_no_l);

  // obj_probs = softmax(obj_logits)
  softmax_k<<<N_OBJ, 256, 0, stream>>>(obj_logits, obj_probs);

  // h_obj = obj_fmaps @ W_obj_proj + obj_probs @ W_emb + b_obj_proj
  mgemm_k<EPI_BIAS, true, false><<<dim3(H / 128, N_OBJ / 128), blk, 0, stream>>>(
      N_OBJ, H, OBJ_DIM, NOC, KP_HOBJ / 32, obj_fmaps, OBJ_DIM, obj_probs, NOC,
      bt_hobj_h, bt_hobj_l, b_obj_proj, h_obj, H,
      nullptr, nullptr, 0, nullptr, nullptr, nullptr);
  // h_rel = vr @ W_rel_proj + b_rel_proj
  mgemm_k<EPI_BIAS, false, false><<<dim3(H / 128, R_REL / 128), blk, 0, stream>>>(
      R_REL, H, OBJ_DIM, 0, KP_HREL / 32, vr, OBJ_DIM, nullptr, 0,
      bt_hrel_h, bt_hrel_l, b_rel_proj, h_rel, H,
      nullptr, nullptr, 0, nullptr, nullptr, nullptr);

  for (int it = 0; it < T_ITERS; ++it) {
    // m_rel = (h_obj[s] + h_obj[o]) @ W_msg_rel
    mgemm_k<EPI_STORE, false, true><<<dim3(H / 128, R_REL / 128), blk, 0, stream>>>(
        R_REL, H, H, 0, KP_MSG / 32, h_obj, H, nullptr, 0,
        bt_mrel_h, bt_mrel_l, nullptr, m_rel, H,
        rel_inds, nullptr, 0, nullptr, nullptr, nullptr);
    // hm = h_rel @ W_msg_obj
    mgemm_k<EPI_STORE, false, false><<<dim3(H / 128, R_REL / 128), blk, 0, stream>>>(
        R_REL, H, H, 0, KP_MSG / 32, h_rel, H, nullptr, 0,
        bt_hm_h, bt_hm_l, nullptr, hm, H,
        nullptr, nullptr, 0, nullptr, nullptr, nullptr);
    // m_obj deterministic gather
    m_obj_gather_k<<<N_OBJ, 256, 0, stream>>>(hm, rel_inds, m_obj);

    // GRU rel gates: sigmoid(m_rel@W[:, :2H] + h_rel@U[:, :2H] + b) -> z, r*h
    mgemm_k<EPI_GATE, true, false><<<dim3(2 * H / 128, R_REL / 128), blk, 0, stream>>>(
        R_REL, 2 * H, H, H, KP_GRU / 32, m_rel, H, h_rel, H,
        bt_gr_h, bt_gr_l, b_gru_rel, nullptr, 0,
        nullptr, h_rel, H, nullptr, z_rel, rh_rel);
    // GRU rel candidate + h update
    mgemm_k<EPI_NEWH, true, false><<<dim3(H / 128, R_REL / 128), blk, 0, stream>>>(
        R_REL, H, H, H, KP_GRU / 32, m_rel, H, rh_rel, H,
        bt_nr_h, bt_nr_l, b_gru_rel + 2 * H, h_rel, H,
        nullptr, h_rel, H, z_rel, nullptr, nullptr);

    // GRU obj gates
    mgemm_k<EPI_GATE, true, false><<<dim3(2 * H / 128, N_OBJ / 128), blk, 0, stream>>>(
        N_OBJ, 2 * H, H, H, KP_GRU / 32, m_obj, H, h_obj, H,
        bt_go_h, bt_go_l, b_gru_obj, nullptr, 0,
        nullptr, h_obj, H, nullptr, z_obj, rh_obj);
    // GRU obj candidate + h update
    mgemm_k<EPI_NEWH, true, false><<<dim3(H / 128, N_OBJ / 128), blk, 0, stream>>>(
        N_OBJ, H, H, H, KP_GRU / 32, m_obj, H, rh_obj, H,
        bt_no_h, bt_no_l, b_gru_obj + 2 * H, h_obj, H,
        nullptr, h_obj, H, z_obj, nullptr, nullptr);
  }

  // classifiers (fp32 vector path, small N)
  gemm_k<128, 8, EPI_BIAS><<<dim3((NRC + 63) / 64, R_REL / 128), blk, 0, stream>>>(
      R_REL, NRC, H, h_rel, H, W_cls_rel, NRC, b_cls_rel, out_rel, NRC);
  gemm_k<64, 4, EPI_BIAS><<<dim3((NOC + 63) / 64, N_OBJ / 64), blk, 0, stream>>>(
      N_OBJ, NOC, H, h_obj, H, W_cls_obj, NOC, b_cls_obj, out_logits, NOC);

  // softmax -> NMS -> preds
  softmax_k<<<N_OBJ, 256, 0, stream>>>(out_logits, obj_probs2);
  nms_k<<<NOC - 1, 512, 0, stream>>>(obj_probs2, boxes, keepmask);
  pred_k<<<2, 256, 0, stream>>>(obj_probs2, keepmask, out_preds);
}

// Round 3
// 1804.149 us; speedup vs baseline: 3.4041x; 1.4406x over previous
//
#include <hip/hip_runtime.h>
#include <math.h>

#define OPI 64
#define RPI 1024
#define N_OBJ 512       // B*OPI
#define R_REL 8192      // B*RPI
#define OBJ_DIM 4096
#define H 512
#define NOC 151
#define NRC 51
#define T_ITERS 3
#define IOU_THRESH 0.3f

typedef unsigned short u16;
typedef unsigned int u32;
typedef __attribute__((ext_vector_type(4))) float f32x4;
typedef __attribute__((ext_vector_type(8))) short bf16x8;
typedef __attribute__((ext_vector_type(4))) short s16x4;
typedef __attribute__((ext_vector_type(8))) short s16x8;

enum { EPI_STORE = 0, EPI_BIAS = 1, EPI_GATE = 3, EPI_NEWH = 4 };

__device__ inline u16 f2bf(float x) {
  u32 u = __float_as_uint(x);
  u32 r = (u + 0x7fffu + ((u >> 16) & 1u)) >> 16;
  return (u16)r;
}
__device__ inline float bf2f(u16 h) { return __uint_as_float(((u32)h) << 16); }

// ---------------------------------------------------------------------------
// Weight prep, coalesced via 64x64 LDS transpose tile.
// out[n][k] = (k<K1 ? W1[k][coloff+n] : k-K1<K2 ? W2[k-K1][coloff+n] : 0), n<ncols
// split into bf16 hi/lo. out has N rows (n >= ncols zero-filled), Kpad cols.
// ---------------------------------------------------------------------------
__global__ __launch_bounds__(256) void prep_bt(
    const float* __restrict__ W1, int ld1, int K1,
    const float* __restrict__ W2, int ld2, int K2,
    int coloff, int ncols, int N, int Kpad,
    u16* __restrict__ outh, u16* __restrict__ outl)
{
  __shared__ float tile[64][65];
  const int k0 = blockIdx.x * 64;
  const int n0 = blockIdx.y * 64;
  const int t = threadIdx.x;
  const int lane = t & 63;
  const int w = t >> 6;
  // read: wave w covers k rows w*16..w*16+15, lanes = consecutive n (coalesced)
#pragma unroll
  for (int p = 0; p < 16; ++p) {
    int kl = w * 16 + p;
    int k = k0 + kl;
    int n = n0 + lane;
    float v = 0.f;
    if (n < ncols) {
      if (k < K1) v = W1[(size_t)k * ld1 + coloff + n];
      else if (k - K1 < K2) v = W2[(size_t)(k - K1) * ld2 + coloff + n];
    }
    tile[kl][lane] = v;
  }
  __syncthreads();
  // write: wave w covers n rows w*16..w*16+15, lanes = consecutive k (coalesced)
#pragma unroll
  for (int p = 0; p < 16; ++p) {
    int nl = w * 16 + p;
    int n = n0 + nl;
    int k = k0 + lane;
    if (n < N && k < Kpad) {
      float v = tile[lane][nl];
      u16 h = f2bf(v);
      outh[(size_t)n * Kpad + k] = h;
      outl[(size_t)n * Kpad + k] = f2bf(v - bf2f(h));
    }
  }
}

// ---------------------------------------------------------------------------
// Split-bf16 MFMA GEMM: C = [A1|A2] @ B, A split hi/lo on the fly,
// B pre-transposed/split bf16 (Bt[N][Kpad] hi/lo).
// C ~= Ah@Bh + Ah@Bl + Al@Bh (fp32 acc). Tile 128x128, 4 waves, 16x16x32 bf16.
// PAIR:  blockIdx.z==1 runs a second independent GEMM (A2/Bt*2/C2, no gather).
// SPLIT: blockIdx.z = K-chunk; raw partials to part[z][M][Npad]; EPI in reduce.
// ---------------------------------------------------------------------------
template<int EPI, bool DUAL, bool GATHER, bool PAIR, bool SPLIT>
__global__ __launch_bounds__(256) void mgemm_k(
    int M, int N, int K1, int K2, int nkt,
    const float* __restrict__ A1, int lda1,
    const float* __restrict__ A2, int lda2,
    const u16* __restrict__ Bth, const u16* __restrict__ Btl,
    const u16* __restrict__ Bth2, const u16* __restrict__ Btl2,
    const float* __restrict__ bias,
    float* __restrict__ C, int ldc, float* __restrict__ C2,
    const int* __restrict__ ridx,
    const float* __restrict__ Hb, int ldh,
    const float* __restrict__ Zin,
    float* __restrict__ Zout, float* __restrict__ RHout,
    float* __restrict__ part, int ktchunk)
{
  __shared__ u16 lAh[128 * 32];
  __shared__ u16 lAl[128 * 32];
  __shared__ u16 lBh[128 * 32];
  __shared__ u16 lBl[128 * 32];
  const int t = threadIdx.x;
  const int lane = t & 63;
  const int wid = t >> 6;
  const int wm = wid >> 1, wn = wid & 1;
  const int m0 = blockIdx.y * 128;
  const int n0 = blockIdx.x * 128;
  const int Kpad = nkt * 32;

  const float* A1p = A1; int ldap = lda1;
  const u16* Bhp = Bth; const u16* Blp = Btl;
  float* Cp = C;
  bool gath = GATHER;
  if (PAIR && blockIdx.z == 1) {
    A1p = A2; ldap = lda2; Bhp = Bth2; Blp = Btl2; Cp = C2; gath = false;
  }

  f32x4 acc[4][4];
#pragma unroll
  for (int m = 0; m < 4; ++m)
#pragma unroll
    for (int n = 0; n < 4; ++n) acc[m][n] = f32x4{0.f, 0.f, 0.f, 0.f};

  const int a_row = t >> 3;
  const int a_kq  = t & 7;
  int g_si[4], g_oi[4];
  if (gath) {
#pragma unroll
    for (int i = 0; i < 4; ++i) {
      int gm = m0 + a_row + i * 32;
      g_si[i] = ridx[gm * 3 + 1];
      g_oi[i] = ridx[gm * 3 + 2];
    }
  }
  const int b_row  = t >> 2;
  const int b_slot = t & 3;

  int ktb = 0, kte = nkt;
  if (SPLIT) {
    ktb = blockIdx.z * ktchunk;
    kte = min(nkt, ktb + ktchunk);
  }

  for (int kt = ktb; kt < kte; ++kt) {
    const int k0 = kt * 32;
    // ---- stage A (fp32 -> split bf16 hi/lo)
#pragma unroll
    for (int i = 0; i < 4; ++i) {
      const int row = a_row + i * 32;
      const int gm = m0 + row;
      const int kk = a_kq * 4;
      const int gk = k0 + kk;
      float x0, x1, x2, x3;
      if (gath) {
        const float4 va = *(const float4*)&A1p[(size_t)g_si[i] * ldap + gk];
        const float4 vb = *(const float4*)&A1p[(size_t)g_oi[i] * ldap + gk];
        x0 = va.x + vb.x; x1 = va.y + vb.y; x2 = va.z + vb.z; x3 = va.w + vb.w;
      } else if (!DUAL) {
        const float4 v = *(const float4*)&A1p[(size_t)gm * ldap + gk];
        x0 = v.x; x1 = v.y; x2 = v.z; x3 = v.w;
      } else {
        if (gk + 3 < K1) {
          const float4 v = *(const float4*)&A1p[(size_t)gm * lda1 + gk];
          x0 = v.x; x1 = v.y; x2 = v.z; x3 = v.w;
        } else if (gk >= K1 && gk + 3 < K1 + K2 && (lda2 & 3) == 0) {
          const float4 v = *(const float4*)&A2[(size_t)gm * lda2 + (gk - K1)];
          x0 = v.x; x1 = v.y; x2 = v.z; x3 = v.w;
        } else {
          float xs[4];
#pragma unroll
          for (int e = 0; e < 4; ++e) {
            int gke = gk + e;
            float xv = 0.f;
            if (gke < K1) xv = A1p[(size_t)gm * lda1 + gke];
            else if (gke < K1 + K2) xv = A2[(size_t)gm * lda2 + (gke - K1)];
            xs[e] = xv;
          }
          x0 = xs[0]; x1 = xs[1]; x2 = xs[2]; x3 = xs[3];
        }
      }
      u16 h0 = f2bf(x0), h1 = f2bf(x1), h2 = f2bf(x2), h3 = f2bf(x3);
      s16x4 vh = { (short)h0, (short)h1, (short)h2, (short)h3 };
      s16x4 vl = { (short)f2bf(x0 - bf2f(h0)), (short)f2bf(x1 - bf2f(h1)),
                   (short)f2bf(x2 - bf2f(h2)), (short)f2bf(x3 - bf2f(h3)) };
      const int base = row * 32 + (((a_kq >> 1) ^ ((row >> 1) & 3)) << 3) + (a_kq & 1) * 4;
      *reinterpret_cast<s16x4*>(&lAh[base]) = vh;
      *reinterpret_cast<s16x4*>(&lAl[base]) = vl;
    }
    // ---- stage B (pre-split bf16)
#pragma unroll
    for (int i = 0; i < 2; ++i) {
      const int row = b_row + i * 64;
      const size_t goff = (size_t)(n0 + row) * Kpad + k0 + b_slot * 8;
      s16x8 vh = *reinterpret_cast<const s16x8*>(&Bhp[goff]);
      s16x8 vl = *reinterpret_cast<const s16x8*>(&Blp[goff]);
      const int base = row * 32 + ((b_slot ^ ((row >> 1) & 3)) << 3);
      *reinterpret_cast<s16x8*>(&lBh[base]) = vh;
      *reinterpret_cast<s16x8*>(&lBl[base]) = vl;
    }
    __syncthreads();
    // ---- fragments + MFMA
    const int fr = lane & 15;
    const int kg = lane >> 4;
    bf16x8 ah[4], al[4], bh[4], bl[4];
#pragma unroll
    for (int m = 0; m < 4; ++m) {
      const int r = wm * 64 + m * 16 + fr;
      const int addr = r * 32 + ((kg ^ ((r >> 1) & 3)) << 3);
      ah[m] = *reinterpret_cast<const bf16x8*>(&lAh[addr]);
      al[m] = *reinterpret_cast<const bf16x8*>(&lAl[addr]);
    }
#pragma unroll
    for (int n = 0; n < 4; ++n) {
      const int r = wn * 64 + n * 16 + fr;
      const int addr = r * 32 + ((kg ^ ((r >> 1) & 3)) << 3);
      bh[n] = *reinterpret_cast<const bf16x8*>(&lBh[addr]);
      bl[n] = *reinterpret_cast<const bf16x8*>(&lBl[addr]);
    }
#pragma unroll
    for (int m = 0; m < 4; ++m)
#pragma unroll
      for (int n = 0; n < 4; ++n) {
        acc[m][n] = __builtin_amdgcn_mfma_f32_16x16x32_bf16(ah[m], bh[n], acc[m][n], 0, 0, 0);
        acc[m][n] = __builtin_amdgcn_mfma_f32_16x16x32_bf16(ah[m], bl[n], acc[m][n], 0, 0, 0);
        acc[m][n] = __builtin_amdgcn_mfma_f32_16x16x32_bf16(al[m], bh[n], acc[m][n], 0, 0, 0);
      }
    __syncthreads();
  }

  // ---- epilogue (C/D layout: col = lane&15, row = (lane>>4)*4 + j)
  const int col = lane & 15;
  const int rb = (lane >> 4) * 4;
  if (SPLIT) {
    const int Npad = gridDim.x * 128;
    float* pp = part + (size_t)blockIdx.z * M * Npad;
#pragma unroll
    for (int m = 0; m < 4; ++m)
#pragma unroll
      for (int n = 0; n < 4; ++n) {
        const int gn = n0 + wn * 64 + n * 16 + col;
#pragma unroll
        for (int j = 0; j < 4; ++j) {
          const int gm = m0 + wm * 64 + m * 16 + rb + j;
          pp[(size_t)gm * Npad + gn] = acc[m][n][j];
        }
      }
    return;
  }
#pragma unroll
  for (int m = 0; m < 4; ++m) {
#pragma unroll
    for (int n = 0; n < 4; ++n) {
      const int gn = n0 + wn * 64 + n * 16 + col;
      if (gn >= N) continue;
#pragma unroll
      for (int j = 0; j < 4; ++j) {
        const int gm = m0 + wm * 64 + m * 16 + rb + j;
        float v = acc[m][n][j];
        if (EPI == EPI_STORE) {
          Cp[(size_t)gm * ldc + gn] = v;
        } else if (EPI == EPI_BIAS) {
          Cp[(size_t)gm * ldc + gn] = v + bias[gn];
        } else if (EPI == EPI_GATE) {
          float g = 1.f / (1.f + expf(-(v + bias[gn])));
          int half = N >> 1;
          if (gn < half) Zout[(size_t)gm * half + gn] = g;
          else RHout[(size_t)gm * half + (gn - half)] = g * Hb[(size_t)gm * ldh + (gn - half)];
        } else if (EPI == EPI_NEWH) {
          float nv = tanhf(v + bias[gn]);
          float z = Zin[(size_t)gm * N + gn];
          float h = Hb[(size_t)gm * ldh + gn];
          Cp[(size_t)gm * ldc + gn] = (1.f - z) * h + z * nv;
        }
      }
    }
  }
}

// ---------------------------------------------------------------------------
// Split-K reduce + epilogue. part[s][M][Npad] raw sums -> EPI applied.
// ---------------------------------------------------------------------------
template<int EPI>
__global__ __launch_bounds__(256) void epi_reduce(
    int S, int M, int N, int Npad,
    const float* __restrict__ part, const float* __restrict__ bias,
    float* __restrict__ C, int ldc,
    const float* __restrict__ Hb, int ldh,
    const float* __restrict__ Zin,
    float* __restrict__ Zout, float* __restrict__ RHout)
{
  int idx = blockIdx.x * 256 + threadIdx.x;
  if (idx >= M * Npad) return;
  int m = idx / Npad;
  int n = idx - m * Npad;
  if (n >= N) return;
  size_t stride = (size_t)M * Npad;
  float v = 0.f;
  for (int s = 0; s < S; ++s) v += part[s * stride + idx];
  if (EPI == EPI_BIAS) {
    C[(size_t)m * ldc + n] = v + bias[n];
  } else if (EPI == EPI_GATE) {
    float g = 1.f / (1.f + expf(-(v + bias[n])));
    int half = N >> 1;
    if (n < half) Zout[(size_t)m * half + n] = g;
    else RHout[(size_t)m * half + (n - half)] = g * Hb[(size_t)m * ldh + (n - half)];
  } else if (EPI == EPI_NEWH) {
    float nv = tanhf(v + bias[n]);
    float z = Zin[(size_t)m * N + n];
    float h = Hb[(size_t)m * ldh + n];
    C[(size_t)m * ldc + n] = (1.f - z) * h + z * nv;
  }
}

// row softmax over NOC=151 columns, one block per row
__global__ __launch_bounds__(256) void softmax_k(const float* __restrict__ X,
                                                 float* __restrict__ P)
{
  int row = blockIdx.x;
  int t = threadIdx.x;
  __shared__ float red[4];
  float x = (t < NOC) ? X[row * NOC + t] : -3.4e38f;
  float m = x;
#pragma unroll
  for (int o = 32; o > 0; o >>= 1) m = fmaxf(m, __shfl_xor(m, o, 64));
  if ((t & 63) == 0) red[t >> 6] = m;
  __syncthreads();
  float mm = fmaxf(fmaxf(red[0], red[1]), fmaxf(red[2], red[3]));
  float e = (t < NOC) ? expf(x - mm) : 0.f;
  float s = e;
#pragma unroll
  for (int o = 32; o > 0; o >>= 1) s += __shfl_xor(s, o, 64);
  __syncthreads();
  if ((t & 63) == 0) red[t >> 6] = s;
  __syncthreads();
  float ss = red[0] + red[1] + red[2] + red[3];
  if (t < NOC) P[row * NOC + t] = e / ss;
}

// deterministic scatter-free m_obj
__global__ __launch_bounds__(256) void m_obj_gather_k(const float* __restrict__ hm,
                                                      const int* __restrict__ ridx,
                                                      float* __restrict__ m_obj)
{
  int n = blockIdx.x;
  int im = n >> 6;
  int col = threadIdx.x;
  float acc0 = 0.f, acc1 = 0.f;
  int r0 = im * RPI, r1 = r0 + RPI;
  for (int r = r0; r < r1; ++r) {
    int s = ridx[r * 3 + 1];
    int o = ridx[r * 3 + 2];
    int cnt = (s == n) + (o == n);
    if (cnt) {
      float f = (float)cnt;
      acc0 = fmaf(f, hm[r * H + col], acc0);
      acc1 = fmaf(f, hm[r * H + col + 256], acc1);
    }
  }
  m_obj[n * H + col] = acc0;
  m_obj[n * H + col + 256] = acc1;
}

// per-class NMS (stable descending bitonic sort + greedy suppression)
__global__ __launch_bounds__(512) void nms_k(const float* __restrict__ probs2,
                                             const float* __restrict__ boxes,
                                             float* __restrict__ keepmask)
{
  int c = blockIdx.x + 1;
  int t = threadIdx.x;
  __shared__ float sc[512];
  __shared__ int   si[512];
  __shared__ float bx0[512], by0[512], bx1[512], by1[512], sar[512];
  __shared__ int   skeep[512];

  sc[t] = probs2[t * NOC + c];
  si[t] = t;
  __syncthreads();

  for (int k = 2; k <= 512; k <<= 1) {
    for (int j = k >> 1; j > 0; j >>= 1) {
      int p = t ^ j;
      if (p > t) {
        float s1 = sc[t], s2 = sc[p];
        int   i1 = si[t], i2 = si[p];
        bool tBefore = (s1 > s2) || (s1 == s2 && i1 < i2);
        bool up = ((t & k) == 0);
        if (up != tBefore) { sc[t] = s2; sc[p] = s1; si[t] = i2; si[p] = i1; }
      }
      __syncthreads();
    }
  }

  {
    const float* b = &boxes[(si[t] * NOC + c) * 4];
    float x0 = b[0], y0 = b[1], x1 = b[2], y1 = b[3];
    bx0[t] = x0; by0[t] = y0; bx1[t] = x1; by1[t] = y1;
    sar[t] = (x1 - x0) * (y1 - y0);
    skeep[t] = 1;
  }
  __syncthreads();

  for (int i = 0; i < 511; ++i) {
    if (skeep[i] && t > i && skeep[t]) {
      float lx = fmaxf(bx0[i], bx0[t]);
      float ly = fmaxf(by0[i], by0[t]);
      float rx = fminf(bx1[i], bx1[t]);
      float ry = fminf(by1[i], by1[t]);
      float w = fmaxf(rx - lx, 0.f);
      float h = fmaxf(ry - ly, 0.f);
      float inter = w * h;
      float iou = inter / (sar[i] + sar[t] - inter + 1e-9f);
      if (iou > IOU_THRESH) skeep[t] = 0;
    }
    __syncthreads();
  }

  keepmask[(c - 1) * N_OBJ + si[t]] = skeep[t] ? 1.f : 0.f;
}

__global__ void pred_k(const float* __restrict__ probs2,
                       const float* __restrict__ keepmask,
                       float* __restrict__ out)
{
  int i = threadIdx.x + blockIdx.x * 256;
  if (i >= N_OBJ) return;
  float best = -1.f;
  int bc = 0;
  for (int c = 0; c < NOC - 1; ++c) {
    float v = keepmask[c * N_OBJ + i] * probs2[i * NOC + c + 1];
    if (v > best) { best = v; bc = c; }
  }
  out[i] = (float)(bc + 1);
}

extern "C" void kernel_launch(void* const* d_in, const int* in_sizes, int n_in,
                              void* d_out, int out_size, void* d_ws, size_t ws_size,
                              hipStream_t stream) {
  const float* obj_fmaps  = (const float*)d_in[1];
  const float* obj_logits = (const float*)d_in[2];
  const int*   rel_inds   = (const int*)d_in[3];
  const float* vr         = (const float*)d_in[4];
  const float* boxes      = (const float*)d_in[5];
  const float* W_obj_proj = (const float*)d_in[6];
  const float* b_obj_proj = (const float*)d_in[7];
  const float* W_rel_proj = (const float*)d_in[8];
  const float* b_rel_proj = (const float*)d_in[9];
  const float* W_emb      = (const float*)d_in[10];
  const float* W_msg_rel  = (const float*)d_in[11];
  const float* W_msg_obj  = (const float*)d_in[12];
  const float* W_gru_obj  = (const float*)d_in[13];
  const float* U_gru_obj  = (const float*)d_in[14];
  const float* b_gru_obj  = (const float*)d_in[15];
  const float* W_gru_rel  = (const float*)d_in[16];
  const float* U_gru_rel  = (const float*)d_in[17];
  const float* b_gru_rel  = (const float*)d_in[18];
  const float* W_cls_rel  = (const float*)d_in[19];
  const float* b_cls_rel  = (const float*)d_in[20];
  const float* W_cls_obj  = (const float*)d_in[21];
  const float* b_cls_obj  = (const float*)d_in[22];

  float* ws = (float*)d_ws;
  const size_t RH = (size_t)R_REL * H;
  const size_t NH = (size_t)N_OBJ * H;
  float* h_rel  = ws;
  float* m_rel  = h_rel  + RH;   // also aliased as split-K partial scratch (disjoint lifetime)
  float* z_rel  = m_rel  + RH;   // aliased with hm (hm dead before z written)
  float* rh_rel = z_rel  + RH;
  float* h_obj  = rh_rel + RH;
  float* m_obj  = h_obj  + NH;
  float* z_obj  = m_obj  + NH;
  float* rh_obj = z_obj  + NH;
  float* obj_probs  = rh_obj + NH;
  float* obj_probs2 = obj_probs  + (size_t)N_OBJ * NOC;
  float* keepmask   = obj_probs2 + (size_t)N_OBJ * NOC;
  float* hm   = z_rel;
  float* part = m_rel;           // max use: 8 x 512 x 1024 = 4,194,304 floats == RH
  float* fend = keepmask + (size_t)(NOC - 1) * N_OBJ;

  // bf16 hi/lo pre-transposed weight buffers
  u16* bt = (u16*)fend;
  const int KP_HOBJ = 4256;   // 4096 + 151 padded to 32
  const int KP_HREL = 4096;
  const int KP_MSG  = 512;
  const int KP_GRU  = 1024;
  const int KP_CLS  = 512;
  u16* p = bt;
  u16* bt_hobj_h = p; p += (size_t)H * KP_HOBJ;      u16* bt_hobj_l = p; p += (size_t)H * KP_HOBJ;
  u16* bt_hrel_h = p; p += (size_t)H * KP_HREL;      u16* bt_hrel_l = p; p += (size_t)H * KP_HREL;
  u16* bt_mrel_h = p; p += (size_t)H * KP_MSG;       u16* bt_mrel_l = p; p += (size_t)H * KP_MSG;
  u16* bt_hm_h   = p; p += (size_t)H * KP_MSG;       u16* bt_hm_l   = p; p += (size_t)H * KP_MSG;
  u16* bt_gr_h   = p; p += (size_t)2 * H * KP_GRU;   u16* bt_gr_l   = p; p += (size_t)2 * H * KP_GRU;
  u16* bt_nr_h   = p; p += (size_t)H * KP_GRU;       u16* bt_nr_l   = p; p += (size_t)H * KP_GRU;
  u16* bt_go_h   = p; p += (size_t)2 * H * KP_GRU;   u16* bt_go_l   = p; p += (size_t)2 * H * KP_GRU;
  u16* bt_no_h   = p; p += (size_t)H * KP_GRU;       u16* bt_no_l   = p; p += (size_t)H * KP_GRU;
  u16* bt_cr_h   = p; p += (size_t)128 * KP_CLS;     u16* bt_cr_l   = p; p += (size_t)128 * KP_CLS;
  u16* bt_co_h   = p; p += (size_t)256 * KP_CLS;     u16* bt_co_l   = p; p += (size_t)256 * KP_CLS;

  float* out_logits = (float*)d_out;                    // 512*151
  float* out_preds  = out_logits + (size_t)N_OBJ * NOC; // 512
  float* out_rel    = out_preds + N_OBJ;                // 8192*51

  dim3 blk(256);
#define PREP(W1, ld1, K1, W2, ld2, K2, coff, NC, NN, KP, oh, ol) \
  prep_bt<<<dim3(((KP) + 63) / 64, ((NN) + 63) / 64), 256, 0, stream>>>( \
      W1, ld1, K1, W2, ld2, K2, coff, NC, NN, KP, oh, ol)

  PREP(W_obj_proj, H, OBJ_DIM, W_emb, H, NOC, 0, H, H, KP_HOBJ, bt_hobj_h, bt_hobj_l);
  PREP(W_rel_proj, H, OBJ_DIM, (const float*)nullptr, 0, 0, 0, H, H, KP_HREL, bt_hrel_h, bt_hrel_l);
  PREP(W_msg_rel, H, H, (const float*)nullptr, 0, 0, 0, H, H, KP_MSG, bt_mrel_h, bt_mrel_l);
  PREP(W_msg_obj, H, H, (const float*)nullptr, 0, 0, 0, H, H, KP_MSG, bt_hm_h, bt_hm_l);
  PREP(W_gru_rel, 3 * H, H, U_gru_rel, 3 * H, H, 0, 2 * H, 2 * H, KP_GRU, bt_gr_h, bt_gr_l);
  PREP(W_gru_rel, 3 * H, H, U_gru_rel, 3 * H, H, 2 * H, H, H, KP_GRU, bt_nr_h, bt_nr_l);
  PREP(W_gru_obj, 3 * H, H, U_gru_obj, 3 * H, H, 0, 2 * H, 2 * H, KP_GRU, bt_go_h, bt_go_l);
  PREP(W_gru_obj, 3 * H, H, U_gru_obj, 3 * H, H, 2 * H, H, H, KP_GRU, bt_no_h, bt_no_l);
  PREP(W_cls_rel, NRC, H, (const float*)nullptr, 0, 0, 0, NRC, 128, KP_CLS, bt_cr_h, bt_cr_l);
  PREP(W_cls_obj, NOC, H, (const float*)nullptr, 0, 0, 0, NOC, 256, KP_CLS, bt_co_h, bt_co_l);

  softmax_k<<<N_OBJ, 256, 0, stream>>>(obj_logits, obj_probs);

#define MG(EPI, DUAL, GATH, PAIR, SPLIT, grid, M, N, K1, K2, nkt, A1, lda1, A2, lda2, \
           Bh, Bl, Bh2, Bl2, bias, C, ldc, C2, ridx, Hb, ldh, Zin, Zo, RHo, part, ktc) \
  mgemm_k<EPI, DUAL, GATH, PAIR, SPLIT><<<grid, blk, 0, stream>>>( \
      M, N, K1, K2, nkt, A1, lda1, A2, lda2, Bh, Bl, Bh2, Bl2, bias, C, ldc, C2, \
      ridx, Hb, ldh, Zin, Zo, RHo, part, ktc)

  // h_obj = obj_fmaps @ W_obj_proj + obj_probs @ W_emb + b  (split-K S=8)
  MG(EPI_STORE, true, false, false, true, dim3(4, 4, 8), N_OBJ, H, OBJ_DIM, NOC, KP_HOBJ / 32,
     obj_fmaps, OBJ_DIM, obj_probs, NOC, bt_hobj_h, bt_hobj_l, nullptr, nullptr,
     nullptr, nullptr, 0, nullptr, nullptr, nullptr, 0, nullptr, nullptr, nullptr, part, 17);
  epi_reduce<EPI_BIAS><<<(N_OBJ * H + 255) / 256, blk, 0, stream>>>(
      8, N_OBJ, H, H, part, b_obj_proj, h_obj, H, nullptr, 0, nullptr, nullptr, nullptr);

  // h_rel = vr @ W_rel_proj + b_rel_proj
  MG(EPI_BIAS, false, false, false, false, dim3(4, 64), R_REL, H, OBJ_DIM, 0, KP_HREL / 32,
     vr, OBJ_DIM, nullptr, 0, bt_hrel_h, bt_hrel_l, nullptr, nullptr,
     b_rel_proj, h_rel, H, nullptr, nullptr, nullptr, 0, nullptr, nullptr, nullptr, nullptr, 0);

  for (int it = 0; it < T_ITERS; ++it) {
    // paired: z=0: m_rel = (h_obj[s]+h_obj[o]) @ W_msg_rel ; z=1: hm = h_rel @ W_msg_obj
    MG(EPI_STORE, false, true, true, false, dim3(4, 64, 2), R_REL, H, H, 0, KP_MSG / 32,
       h_obj, H, h_rel, H, bt_mrel_h, bt_mrel_l, bt_hm_h, bt_hm_l,
       nullptr, m_rel, H, hm, rel_inds, nullptr, 0, nullptr, nullptr, nullptr, nullptr, 0);
    m_obj_gather_k<<<N_OBJ, 256, 0, stream>>>(hm, rel_inds, m_obj);

    // GRU rel gates
    MG(EPI_GATE, true, false, false, false, dim3(8, 64), R_REL, 2 * H, H, H, KP_GRU / 32,
       m_rel, H, h_rel, H, bt_gr_h, bt_gr_l, nullptr, nullptr,
       b_gru_rel, nullptr, 0, nullptr, nullptr, h_rel, H, nullptr, z_rel, rh_rel, nullptr, 0);
    // GRU rel candidate + h update
    MG(EPI_NEWH, true, false, false, false, dim3(4, 64), R_REL, H, H, H, KP_GRU / 32,
       m_rel, H, rh_rel, H, bt_nr_h, bt_nr_l, nullptr, nullptr,
       b_gru_rel + 2 * H, h_rel, H, nullptr, nullptr, h_rel, H, z_rel, nullptr, nullptr, nullptr, 0);

    // GRU obj gates (split-K S=8)
    MG(EPI_STORE, true, false, false, true, dim3(8, 4, 8), N_OBJ, 2 * H, H, H, KP_GRU / 32,
       m_obj, H, h_obj, H, bt_go_h, bt_go_l, nullptr, nullptr,
       nullptr, nullptr, 0, nullptr, nullptr, nullptr, 0, nullptr, nullptr, nullptr, part, 4);
    epi_reduce<EPI_GATE><<<(N_OBJ * 2 * H + 255) / 256, blk, 0, stream>>>(
        8, N_OBJ, 2 * H, 2 * H, part, b_gru_obj, nullptr, 0, h_obj, H, nullptr, z_obj, rh_obj);
    // GRU obj candidate + h update (split-K S=8)
    MG(EPI_STORE, true, false, false, true, dim3(4, 4, 8), N_OBJ, H, H, H, KP_GRU / 32,
       m_obj, H, rh_obj, H, bt_no_h, bt_no_l, nullptr, nullptr,
       nullptr, nullptr, 0, nullptr, nullptr, nullptr, 0, nullptr, nullptr, nullptr, part, 4);
    epi_reduce<EPI_NEWH><<<(N_OBJ * H + 255) / 256, blk, 0, stream>>>(
        8, N_OBJ, H, H, part, b_gru_obj + 2 * H, h_obj, H, h_obj, H, z_obj, nullptr, nullptr);
  }

  // rel_logits = h_rel @ W_cls_rel + b (N=51, padded bt to 128)
  MG(EPI_BIAS, false, false, false, false, dim3(1, 64), R_REL, NRC, H, 0, KP_CLS / 32,
     h_rel, H, nullptr, 0, bt_cr_h, bt_cr_l, nullptr, nullptr,
     b_cls_rel, out_rel, NRC, nullptr, nullptr, nullptr, 0, nullptr, nullptr, nullptr, nullptr, 0);
  // obj_logits_out = h_obj @ W_cls_obj + b (N=151, padded bt to 256, split-K S=4)
  MG(EPI_STORE, false, false, false, true, dim3(2, 4, 4), N_OBJ, NOC, H, 0, KP_CLS / 32,
     h_obj, H, nullptr, 0, bt_co_h, bt_co_l, nullptr, nullptr,
     nullptr, nullptr, 0, nullptr, nullptr, nullptr, 0, nullptr, nullptr, nullptr, part, 4);
  epi_reduce<EPI_BIAS><<<(N_OBJ * 256 + 255) / 256, blk, 0, stream>>>(
      4, N_OBJ, NOC, 256, part, b_cls_obj, out_logits, NOC, nullptr, 0, nullptr, nullptr, nullptr);

  // softmax -> NMS -> preds
  softmax_k<<<N_OBJ, 256, 0, stream>>>(out_logits, obj_probs2);
  nms_k<<<NOC - 1, 512, 0, stream>>>(obj_probs2, boxes, keepmask);
  pred_k<<<2, 256, 0, stream>>>(obj_probs2, keepmask, out_preds);
}